// Round 14
// baseline (214.630 us; speedup 1.0000x reference)
//
#include <hip/hip_runtime.h>
#include <stdint.h>

#define NG 4
#define NK 160
#define GD 128
#define ED 512
#define BB 16
#define TT 4096
static constexpr size_t ZSZ = (size_t)BB * ED * TT;           // 33554432

typedef float f32x4 __attribute__((ext_vector_type(4)));

// d_out FLOAT32: [0,ZSZ) z_q | [ZSZ] loss | codes after.
// ws (floats): [0,1024) bsum | [1024,1664) sc | [2048, 2048+81920) ct[g][d][k]

// ---------------- prep: transpose codebook to [g][d][k] + codeword norms ---
__global__ void prep_kernel(const float* __restrict__ cb, float* __restrict__ sc,
                            float* __restrict__ ct) {
  int i = blockIdx.x * 256 + threadIdx.x;                 // 81920 total
  int g = i / (GD * NK), r = i % (GD * NK), d = r / NK, k = r % NK;
  ct[i] = cb[((size_t)g * NK + k) * GD + d];
  if (i < NG * NK) {
    const float* c = cb + (size_t)i * GD;
    float s = 0.f;
    for (int dd = 0; dd < GD; ++dd) s = fmaf(c[dd], c[dd], s);
    sc[i] = s;
  }
}

// ---- pipelined operand access macros (pure dataflow, no asm) -------------
#define XLOAD(R_, DD) R_ = *(const f32x4*)(xp + (size_t)(DD) * TT)

#define CLOAD(P_, DD)                                                      \
  do {                                                                     \
    const float* cwp_ = ctg + (size_t)(DD) * NK + kbase;                   \
    P_##0 = *(const f32x4*)&cwp_[0];                                       \
    P_##1 = *(const f32x4*)&cwp_[4];                                       \
    P_##2 = *(const f32x4*)&cwp_[8];                                       \
    P_##3 = *(const f32x4*)&cwp_[12];                                      \
    P_##4 = *(const f32x4*)&cwp_[16];                                      \
  } while (0)

#define COMP(XV, P_)                                                       \
  do {                                                                     \
    _Pragma("unroll") for (int i_ = 0; i_ < 4; ++i_)                       \
        sxa[i_] = fmaf((XV)[i_], (XV)[i_], sxa[i_]);                       \
    _Pragma("unroll") for (int i_ = 0; i_ < 4; ++i_) {                     \
      const float xf_ = (XV)[i_];                                          \
      _Pragma("unroll") for (int e_ = 0; e_ < 4; ++e_) {                   \
        acc[i_][e_] = fmaf(xf_, (P_##0)[e_], acc[i_][e_]);                 \
        acc[i_][4 + e_] = fmaf(xf_, (P_##1)[e_], acc[i_][4 + e_]);         \
        acc[i_][8 + e_] = fmaf(xf_, (P_##2)[e_], acc[i_][8 + e_]);         \
        acc[i_][12 + e_] = fmaf(xf_, (P_##3)[e_], acc[i_][12 + e_]);       \
        acc[i_][16 + e_] = fmaf(xf_, (P_##4)[e_], acc[i_][16 + e_]);       \
      }                                                                    \
    }                                                                      \
  } while (0)

// ---------------- main: 512 thr, 8 waves x 20 codes, 4 tok/lane ------------
// Zero barriers in the k-loop. 8-deep x register ring (reload right after
// use -> ~1400cy cover >= HBM latency); 2-deep code double-buffer (cA/cB by
// unroll parity) so codes(dd+1) are always in flight during COMP(dd).
__global__ __launch_bounds__(512) void vq_kernel(const float* __restrict__ xin,
                                                 const float* __restrict__ cb,
                                                 const float* __restrict__ sc,
                                                 const float* __restrict__ ct,
                                                 float* __restrict__ out,
                                                 float* __restrict__ bsum) {
  __shared__ float bestW[8 * 256];                        // 8 KB
  __shared__ int bikW[8 * 256];                           // 8 KB
  __shared__ int kfS[256];
  __shared__ float wred[4];

  const int tid = (int)threadIdx.x;
  const int w = tid >> 6;                                 // wave 0..7
  const int l = tid & 63;                                 // lane
  const int g = (int)(blockIdx.x >> 8);
  const int tb = (int)(blockIdx.x & 255);
  const int b = tb >> 4;
  const int t0 = (tb & 15) << 8;                          // 256-token window

  const float* xp = xin + ((size_t)(b * ED + g * GD)) * TT + t0 + l * 4;
  const float* ctg = ct + (size_t)g * GD * NK;
  const int kbase = __builtin_amdgcn_readfirstlane(w) * 20;  // wave-uniform

  float acc[4][20];
#pragma unroll
  for (int i = 0; i < 4; ++i)
#pragma unroll
    for (int j = 0; j < 20; ++j) acc[i][j] = 0.f;
  float sxa[4] = {0.f, 0.f, 0.f, 0.f};

  f32x4 x0, x1, x2, x3, x4, x5, x6, x7;
  f32x4 cA0, cA1, cA2, cA3, cA4, cB0, cB1, cB2, cB3, cB4;

  // prologue: fill x ring (dd 0..7) and first code set
  XLOAD(x0, 0); XLOAD(x1, 1); XLOAD(x2, 2); XLOAD(x3, 3);
  XLOAD(x4, 4); XLOAD(x5, 5); XLOAD(x6, 6); XLOAD(x7, 7);
  CLOAD(cA, 0);

#pragma unroll 1
  for (int dd8 = 0; dd8 < 120; dd8 += 8) {                // dd 0..119
    CLOAD(cB, dd8 + 1); COMP(x0, cA); XLOAD(x0, dd8 + 8);
    CLOAD(cA, dd8 + 2); COMP(x1, cB); XLOAD(x1, dd8 + 9);
    CLOAD(cB, dd8 + 3); COMP(x2, cA); XLOAD(x2, dd8 + 10);
    CLOAD(cA, dd8 + 4); COMP(x3, cB); XLOAD(x3, dd8 + 11);
    CLOAD(cB, dd8 + 5); COMP(x4, cA); XLOAD(x4, dd8 + 12);
    CLOAD(cA, dd8 + 6); COMP(x5, cB); XLOAD(x5, dd8 + 13);
    CLOAD(cB, dd8 + 7); COMP(x6, cA); XLOAD(x6, dd8 + 14);
    CLOAD(cA, dd8 + 8); COMP(x7, cB); XLOAD(x7, dd8 + 15);
  }
  // epilogue: dd 120..127 (x ring holds them; prefetch codes to 127 only)
  CLOAD(cB, 121); COMP(x0, cA);
  CLOAD(cA, 122); COMP(x1, cB);
  CLOAD(cB, 123); COMP(x2, cA);
  CLOAD(cA, 124); COMP(x3, cB);
  CLOAD(cB, 125); COMP(x4, cA);
  CLOAD(cA, 126); COMP(x5, cB);
  CLOAD(cB, 127); COMP(x6, cA);
  COMP(x7, cB);

  // ---- per-wave argmin over its 20 codes (ascending k, strict <) ----
  const float* scw = sc + g * NK + kbase;
  float best[4] = {3.4e38f, 3.4e38f, 3.4e38f, 3.4e38f};
  int bik[4] = {0, 0, 0, 0};
#pragma unroll
  for (int j = 0; j < 20; ++j) {
    const float scv = scw[j];
#pragma unroll
    for (int i = 0; i < 4; ++i) {
      const float dv = (sxa[i] + scv) - 2.0f * acc[i][j]; // ref formula order
      if (dv < best[i]) { best[i] = dv; bik[i] = kbase + j; }
    }
  }

  // ---- cross-wave merge ----
  *(f32x4*)&bestW[w * 256 + l * 4] = (f32x4){best[0], best[1], best[2], best[3]};
#pragma unroll
  for (int i = 0; i < 4; ++i) bikW[w * 256 + l * 4 + i] = bik[i];
  __syncthreads();

  if (tid < 256) {                                        // token owner = tid
    float bf = bestW[tid];
    int kf = bikW[tid];
#pragma unroll
    for (int ww = 1; ww < 8; ++ww) {                      // ascending k order
      float bw = bestW[ww * 256 + tid];
      int kw = bikW[ww * 256 + tid];
      if (bw < bf) { bf = bw; kf = kw; }                  // first-min kept
    }
    kfS[tid] = kf;

    // codes_out[b, g, t0+tid]
    out[ZSZ + 1 + ((size_t)(b * NG + g)) * TT + t0 + tid] = (float)kf;

    // loss partial: deterministic wave reduce (waves 0..3)
    float s = bf;
#pragma unroll
    for (int off = 32; off > 0; off >>= 1) s += __shfl_down(s, off, 64);
    if (l == 0) wred[w] = s;
  }
  __syncthreads();

  // ---- z_q write split across all 512 threads (half the d-range each) ----
  {
    const int tok = tid & 255;
    const int half = tid >> 8;                            // 0: d<64, 1: d>=64
    const int kf = kfS[tok];
    const f32x4* cw = (const f32x4*)(cb + ((size_t)g * NK + kf) * GD) + half * 16;
    float* zbase = out + ((size_t)(b * ED + g * GD) + (size_t)half * 64) * TT
                   + t0 + tok;
#pragma unroll 4
    for (int d4 = 0; d4 < 16; ++d4) {
      f32x4 v = cw[d4];
      zbase[(size_t)(4 * d4 + 0) * TT] = v[0];
      zbase[(size_t)(4 * d4 + 1) * TT] = v[1];
      zbase[(size_t)(4 * d4 + 2) * TT] = v[2];
      zbase[(size_t)(4 * d4 + 3) * TT] = v[3];
    }
  }

  if (tid == 0)
    bsum[blockIdx.x] = ((wred[0] + wred[1]) + wred[2]) + wred[3];
}

// ---------------- loss ----------------
__global__ __launch_bounds__(64) void loss_kernel(const float* __restrict__ bsum,
                                                  float* __restrict__ out) {
  float s = 0.f;
  for (int j = 0; j < 16; ++j) s += bsum[threadIdx.x + 64 * j];
#pragma unroll
  for (int off = 32; off > 0; off >>= 1) s += __shfl_down(s, off, 64);
  if (threadIdx.x == 0) out[ZSZ] = 1.25f * s / (float)ZSZ;
}

extern "C" void kernel_launch(void* const* d_in, const int* in_sizes, int n_in,
                              void* d_out, int out_size, void* d_ws, size_t ws_size,
                              hipStream_t stream) {
  const float* xin = (const float*)d_in[0];
  const float* cb  = (const float*)d_in[1];
  float* out  = (float*)d_out;
  float* bsum = (float*)d_ws;            // 1024
  float* sc   = (float*)d_ws + 1024;     // 640
  float* ct   = (float*)d_ws + 2048;     // 81920

  prep_kernel<<<320, 256, 0, stream>>>(cb, sc, ct);
  vq_kernel<<<1024, 512, 0, stream>>>(xin, cb, sc, ct, out, bsum);
  loss_kernel<<<1, 64, 0, stream>>>(bsum, out);
}